// Round 1
// baseline (237.838 us; speedup 1.0000x reference)
//
#include <hip/hip_runtime.h>

// Problem constants (fixed by the reference)
constexpr int C_ = 2048;
constexpr int H_ = 16;
constexpr int W_ = 16;
constexpr int F_ = 64;
constexpr int P_ = 256;              // samples per complex
constexpr int MAP4 = H_ * W_ * F_ / 4;  // 4096 float4 = 64 KB

// One block per complex. 256 threads.
// Phase 1: stage map[c] (64 KB) into LDS, compute per-sample coeffs.
// Phase 2: 16 threads per sample (float4 over F), 16 samples/iter, 16 iters.
__global__ __launch_bounds__(256) void ngf_fetch_kernel(
    const float* __restrict__ map_,
    const float* __restrict__ u_,
    const float* __restrict__ v_,
    float* __restrict__ out_) {
  __shared__ float4 smap[MAP4];   // 64 KB: map[c] as [H][W][F/4] float4
  __shared__ float s_fx[P_];
  __shared__ float s_fy[P_];
  __shared__ int   s_ix[P_];      // (y0*W + x0) * (F/4), in float4 units

  const int c = blockIdx.x;
  const int tid = threadIdx.x;

  // ---- stage map tile: 4096 float4 / 256 threads = 16 each, coalesced ----
  const float4* gmap = (const float4*)(map_ + (size_t)c * (H_ * W_ * F_));
#pragma unroll
  for (int i = 0; i < MAP4 / 256; ++i) {
    smap[i * 256 + tid] = gmap[i * 256 + tid];
  }

  // ---- per-sample coefficients (one sample per thread) ----
  {
    const float x = u_[(size_t)c * P_ + tid] * (float)(W_ - 1);
    const float y = v_[(size_t)c * P_ + tid] * (float)(H_ - 1);
    int x0 = (int)floorf(x);
    int y0 = (int)floorf(y);
    x0 = x0 < 0 ? 0 : (x0 > W_ - 2 ? W_ - 2 : x0);
    y0 = y0 < 0 ? 0 : (y0 > H_ - 2 ? H_ - 2 : y0);
    s_fx[tid] = x - (float)x0;
    s_fy[tid] = y - (float)y0;
    s_ix[tid] = (y0 * W_ + x0) * (F_ / 4);
  }
  __syncthreads();

  // ---- gather + lerp + store ----
  float4* gout = (float4*)(out_ + (size_t)c * (P_ * F_));
  const int f = tid & 15;        // float4 index along feature dim (0..15)
  const int sbase = tid >> 4;    // 0..15

#pragma unroll
  for (int it = 0; it < 16; ++it) {
    const int s = it * 16 + sbase;           // sample index
    const float fx = s_fx[s];
    const float fy = s_fy[s];
    const int ix = s_ix[s] + f;

    const float4 g00 = smap[ix];
    const float4 g01 = smap[ix + (F_ / 4)];            // x0+1
    const float4 g10 = smap[ix + W_ * (F_ / 4)];       // y0+1
    const float4 g11 = smap[ix + (W_ + 1) * (F_ / 4)]; // y0+1, x0+1

    const float wx1 = fx, wx0 = 1.0f - fx;
    const float wy1 = fy, wy0 = 1.0f - fy;

    float4 r;
    r.x = (g00.x * wx0 + g01.x * wx1) * wy0 + (g10.x * wx0 + g11.x * wx1) * wy1;
    r.y = (g00.y * wx0 + g01.y * wx1) * wy0 + (g10.y * wx0 + g11.y * wx1) * wy1;
    r.z = (g00.z * wx0 + g01.z * wx1) * wy0 + (g10.z * wx0 + g11.z * wx1) * wy1;
    r.w = (g00.w * wx0 + g01.w * wx1) * wy0 + (g10.w * wx0 + g11.w * wx1) * wy1;

    gout[s * (F_ / 4) + f] = r;   // wave writes 1 KB contiguous
  }
}

extern "C" void kernel_launch(void* const* d_in, const int* in_sizes, int n_in,
                              void* d_out, int out_size, void* d_ws, size_t ws_size,
                              hipStream_t stream) {
  const float* map_ = (const float*)d_in[0];
  const float* u_   = (const float*)d_in[1];
  const float* v_   = (const float*)d_in[2];
  float* out_ = (float*)d_out;

  ngf_fetch_kernel<<<C_, 256, 0, stream>>>(map_, u_, v_, out_);
}